// Round 7
// baseline (1173.014 us; speedup 1.0000x reference)
//
#include <hip/hip_runtime.h>
#include <math.h>

#define B_ 32
#define T_ 3000
#define C_ 512
#define THf 1.0f
#define KW 2560   // 5*512 flattened conv K

typedef _Float16 f16;
typedef _Float16 half8 __attribute__((ext_vector_type(8)));
typedef float floatx4 __attribute__((ext_vector_type(4)));

#define GLOBAL_AS __attribute__((address_space(1)))
#define LDS_AS __attribute__((address_space(3)))

#define CS_SIZE  ((size_t)B_ * T_ * C_)
#define MASK_OFF CS_SIZE
#define LOSS_OFF (CS_SIZE + (size_t)B_ * T_)

// lo-part scale: 2^6 (keeps lo parts f16-normal; hi/64 derivable exactly)
#define LOSC 64.0f

// ================= PATH A ws layout (needs ~207 MB) ========================
// hs16 [b][ic32][t][64 f16] (32 hi + 32 lo64, 16B-chunks slot-swizzled by (t+2)&7)
#define HS16_ELEMS   ((size_t)B_ * 16 * 3000 * 64)      // 98,304,000 f16
#define HS16_ZEL     HS16_ELEMS                          // 64-f16 zero row
#define HS16_BYTES   (2 * (HS16_ELEMS + 64))             // 196,608,128
#define A_WHI_OFF    HS16_BYTES
#define A_WLO_OFF    (A_WHI_OFF + 2621440)
#define A_PL_OFF     (A_WLO_OFF + 2621440)
#define A_ALPHA_OFF  (A_PL_OFF + 3072000)
#define A_SEGI_OFF   (A_ALPHA_OFF + 384000)
#define A_SEGW_OFF   (A_SEGI_OFF + 768000)
#define A_TOT_OFF    (A_SEGW_OFF + 768000)
#define A_WS_NEED    (A_TOT_OFF + 128)

// ================= PATH B ws layout (fallback, ~10 MB) =====================
#define B_WHI_OFF   0
#define B_WLO_OFF   2621440
#define B_PL_OFF    5242880
#define B_ALPHA_OFF 8314880
#define B_SEGI_OFF  8698880
#define B_SEGW_OFF  9466880
#define B_TOT_OFF   10234880

// ---------------- W prep: [o][i][k] fp32 -> [k][i8][o][ie] f16 hi/lo64 -----
__global__ __launch_bounds__(256) void w_prep_kernel(
    const float* __restrict__ W, f16* __restrict__ whi, f16* __restrict__ wlo)
{
    int idx = blockIdx.x * 256 + threadIdx.x;
    if (idx >= 512 * KW) return;
    int ie = idx & 7;
    int o  = (idx >> 3) & 511;
    int i8 = (idx >> 12) & 63;
    int k  = idx >> 18;
    int i  = i8 * 8 + ie;
    float w = W[o * KW + i * 5 + k];
    f16 h = (f16)w;
    whi[idx] = h;
    wlo[idx] = (f16)((w - (float)h) * LOSC);
}

// ---------------- hs split: fp32 -> hi/lo64 f16, chunk-swizzled, vectorized
__global__ __launch_bounds__(256) void hs_split_kernel(
    const float* __restrict__ hs, f16* __restrict__ hs16)
{
    int idx = blockIdx.x * 256 + threadIdx.x;   // < 32*16*3000*4 = 6,144,000
    if (idx < 8) {
        half8 z = {(f16)0.f, (f16)0.f, (f16)0.f, (f16)0.f,
                   (f16)0.f, (f16)0.f, (f16)0.f, (f16)0.f};
        *(half8*)(hs16 + HS16_ZEL + idx * 8) = z;
    }
    if (idx >= B_ * 16 * 3000 * 4) return;
    int ch  = idx & 3;
    int row = idx >> 2;
    int t   = row % 3000;
    int bic = row / 3000;
    int b   = bic >> 4;
    int ic  = bic & 15;
    const float* src = hs + ((size_t)b * 3000 + t) * 512 + ic * 32 + ch * 8;
    float4 v0 = *(const float4*)src;
    float4 v1 = *(const float4*)(src + 4);
    float vv[8] = {v0.x, v0.y, v0.z, v0.w, v1.x, v1.y, v1.z, v1.w};
    half8 hh, ll;
#pragma unroll
    for (int q = 0; q < 8; ++q) {
        f16 x = (f16)vv[q];
        hh[q] = x;
        ll[q] = (f16)((vv[q] - (float)x) * LOSC);
    }
    int m7 = (t + 2) & 7;
    size_t rb = (size_t)row * 64;
    *(half8*)(hs16 + rb + (size_t)((ch ^ m7) * 8))       = hh;
    *(half8*)(hs16 + rb + (size_t)(((ch + 4) ^ m7) * 8)) = ll;
}

// ---------------- PATH A conv: 16x16x32 MFMA, single acc, 3 blocks/CU ------
// block 128t x 128o, 4 waves (2m x 2n) of 64x64; K=32/step, 80 steps.
// LDS f16 units: A[8704] @0 (136 rows x 64, single-buffered),
//                W @8704: [buf 2][arr(hi/lo) 2][4096]  (kc 4 x o 128 x ie 8)
__global__ __launch_bounds__(256, 3) void conv_alpha_mfma_a(
    const f16* __restrict__ hs16, const f16* __restrict__ whi_g,
    const f16* __restrict__ wlo_g, const float* __restrict__ conv_b,
    const float* __restrict__ lin_w, float* __restrict__ pl)
{
    __shared__ f16 sm[25088];   // 50,176 B -> 3 blocks/CU

    int tid = threadIdx.x;
    int bid = blockIdx.x;
    int nb  = bid & 3;
    int mtg = bid >> 2;
    int b   = mtg / 24;
    int mt  = mtg - b * 24;
    int t0  = mt * 128;

    int wid = tid >> 6, l = tid & 63;
    int wm = wid >> 1, wn = wid & 1;
    int l15 = l & 15, l4 = l >> 4;
    int o0 = nb * 128;

    floatx4 acc[4][4];
#pragma unroll
    for (int mf = 0; mf < 4; ++mf)
#pragma unroll
        for (int nf = 0; nf < 4; ++nf) acc[mf][nf] = (floatx4)0.f;

    // async A tile (single buffer): 17 x 1KB (5 instrs/wave, last duplicated)
    auto issue_a = [&](int icn) {
        const f16* hbase = hs16 + ((size_t)(b * 16 + icn)) * 3000 * 64;
        f16* abase = sm;
#pragma unroll
        for (int jj = 0; jj < 4; ++jj) {
            int j = wid + jj * 4;
            int r = j * 8 + (l >> 3);
            int t = t0 - 2 + r;
            const f16* gsrc = ((unsigned)t < 3000u)
                ? hbase + (size_t)t * 64 + (l & 7) * 8
                : hs16 + HS16_ZEL + (l & 7) * 8;
            __builtin_amdgcn_global_load_lds((const GLOBAL_AS void*)gsrc,
                                             (LDS_AS void*)(abase + j * 512), 16, 0, 0);
        }
        {
            int j = (wid == 0) ? 16 : (wid + 12);
            int r = j * 8 + (l >> 3);
            int t = t0 - 2 + r;
            const f16* gsrc = ((unsigned)t < 3000u)
                ? hbase + (size_t)t * 64 + (l & 7) * 8
                : hs16 + HS16_ZEL + (l & 7) * 8;
            __builtin_amdgcn_global_load_lds((const GLOBAL_AS void*)gsrc,
                                             (LDS_AS void*)(abase + j * 512), 16, 0, 0);
        }
    };
    // async W tile: step s = ic*5+k -> 16 x 1KB regions (4 instrs/wave)
    auto issue_w = [&](int s2) {
        int buf = s2 & 1;
        int ic2 = s2 / 5, k2 = s2 - ic2 * 5;
#pragma unroll
        for (int rr = 0; rr < 4; ++rr) {
            int r = wid * 4 + rr;
            int arr = r >> 3, kc = (r >> 1) & 3, oh = r & 1;
            const f16* gsrc = (arr ? wlo_g : whi_g) +
                ((size_t)((k2 * 64 + ic2 * 4 + kc) * 512 + o0 + oh * 64 + l)) * 8;
            f16* ldst = sm + 8704 + (buf * 2 + arr) * 4096 + (kc * 128 + oh * 64) * 8;
            __builtin_amdgcn_global_load_lds((const GLOBAL_AS void*)gsrc,
                                             (LDS_AS void*)ldst, 16, 0, 0);
        }
    };

    issue_a(0);
    issue_w(0);
    __syncthreads();

    const f16 inv64 = (f16)0.015625f;

    for (int s = 0; s < 80; ++s) {
        int ic = s / 5, k = s - ic * 5;
        int wbuf = s & 1;
        bool aStep = (k == 4);

        if (!aStep && s + 1 < 80) issue_w(s + 1);

        const f16* Ab = sm;
        const f16* Wh = sm + 8704 + (wbuf * 2 + 0) * 4096;
        const f16* Wl = sm + 8704 + (wbuf * 2 + 1) * 4096;
        int m7 = (l15 + k) & 7;
        int sh = (l4 ^ m7) * 8;
        int sl = ((l4 + 4) ^ m7) * 8;

        half8 ah[4], al[4], bh[4], bl[4];
#pragma unroll
        for (int f = 0; f < 4; ++f) {
            int r = wm * 64 + f * 16 + l15 + k;
            ah[f] = *(const half8*)(Ab + r * 64 + sh);
            al[f] = *(const half8*)(Ab + r * 64 + sl);
            int wrow = l4 * 128 + wn * 64 + f * 16 + l15;
            bh[f] = *(const half8*)(Wh + wrow * 8);
            bl[f] = *(const half8*)(Wl + wrow * 8);
        }
        half8 bhd[4];
#pragma unroll
        for (int nf = 0; nf < 4; ++nf) bhd[nf] = bh[nf] * inv64;

        __builtin_amdgcn_s_setprio(1);
#pragma unroll
        for (int mf = 0; mf < 4; ++mf) {
            half8 ahd = ah[mf] * inv64;
#pragma unroll
            for (int nf = 0; nf < 4; ++nf) {
                acc[mf][nf] = __builtin_amdgcn_mfma_f32_16x16x32_f16(
                    ah[mf], bh[nf], acc[mf][nf], 0, 0, 0);
                acc[mf][nf] = __builtin_amdgcn_mfma_f32_16x16x32_f16(
                    al[mf], bhd[nf], acc[mf][nf], 0, 0, 0);
                acc[mf][nf] = __builtin_amdgcn_mfma_f32_16x16x32_f16(
                    ahd, bl[nf], acc[mf][nf], 0, 0, 0);
            }
        }
        __builtin_amdgcn_s_setprio(0);

        if (aStep) {
            __syncthreads();                 // all waves done reading A tile ic
            if (ic + 1 < 16) issue_a(ic + 1);
            if (s + 1 < 80) issue_w(s + 1);
            __syncthreads();                 // per-wave vmcnt(0) drain -> landed
        } else {
            __syncthreads();
        }
    }

    // epilogue: relu(c+cb)*lw, reduce over o (16 lanes), scatter rows
    float cb[4], lw[4];
#pragma unroll
    for (int nf = 0; nf < 4; ++nf) {
        int o = o0 + wn * 64 + nf * 16 + l15;
        cb[nf] = conv_b[o];
        lw[nf] = lin_w[o];
    }
    float* plb = pl + (size_t)(nb * 2 + wn) * (B_ * T_) + b * T_;
#pragma unroll
    for (int mf = 0; mf < 4; ++mf) {
#pragma unroll
        for (int reg = 0; reg < 4; ++reg) {
            float v = 0.f;
#pragma unroll
            for (int nf = 0; nf < 4; ++nf) {
                float c = acc[mf][nf][reg];
                v += fmaxf(c + cb[nf], 0.f) * lw[nf];
            }
            v += __shfl_xor(v, 1);
            v += __shfl_xor(v, 2);
            v += __shfl_xor(v, 4);
            v += __shfl_xor(v, 8);
            int trow = t0 + wm * 64 + mf * 16 + l4 * 4 + reg;
            if (l15 == reg && trow < T_) plb[trow] = v;
        }
    }
}

// ---------------- PATH B conv (fallback, 16x16x32, in-kernel conversion) ---
#define A_ROWS 132
#define ALO_OFF_E  8448
#define WB_OFF_E   16896
#define WB_ARR_E   4096

__global__ __launch_bounds__(256, 2) void conv_alpha_mfma_b(
    const float* __restrict__ hs, const f16* __restrict__ whi_g,
    const f16* __restrict__ wlo_g, const float* __restrict__ conv_b,
    const float* __restrict__ lin_w, float* __restrict__ pl)
{
    __shared__ f16 sm[33280];
    f16* Ahi = sm;
    f16* Alo = sm + ALO_OFF_E;
    f16* Wb  = sm + WB_OFF_E;

    int tid = threadIdx.x;
    int bid = blockIdx.x;
    int nb  = bid & 3;
    int mtg = bid >> 2;
    int b   = mtg / 24;
    int mt  = mtg - b * 24;
    int t0  = mt * 128;

    int wid = tid >> 6, l = tid & 63;
    int wm = wid >> 1, wn = wid & 1;
    int l15 = l & 15, l4 = l >> 4;

    const float* hb = hs + (size_t)b * T_ * C_;
    int o0 = nb * 128;

    floatx4 acc1[4][4], acc2[4][4];
#pragma unroll
    for (int mf = 0; mf < 4; ++mf)
#pragma unroll
        for (int nf = 0; nf < 4; ++nf) {
            acc1[mf][nf] = (floatx4)0.f;
            acc2[mf][nf] = (floatx4)0.f;
        }

    auto issue_w = [&](int s2) {
        int buf = s2 & 1;
        int ic2 = s2 / 10, kk2 = s2 % 10;
        int k2 = kk2 >> 1, sub2 = kk2 & 1;
        int i8b = ic2 * 8 + sub2 * 4;
#pragma unroll
        for (int rr = 0; rr < 4; ++rr) {
            int r = wid * 4 + rr;
            int arr = r >> 3, kc = (r >> 1) & 3, oh = r & 1;
            const f16* gsrc = (arr ? wlo_g : whi_g) +
                ((size_t)((k2 * 64 + i8b + kc) * 512 + o0 + oh * 64 + l)) * 8;
            f16* ldst = Wb + (buf * 2 + arr) * WB_ARR_E + (kc * 128 + oh * 64) * 8;
            __builtin_amdgcn_global_load_lds((const GLOBAL_AS void*)gsrc,
                                             (LDS_AS void*)ldst, 16, 0, 0);
        }
    };

    issue_w(0);

    for (int s = 0; s < 80; ++s) {
        int ic = s / 10, kk = s % 10;
        int k = kk >> 1, sub = kk & 1;
        int buf = s & 1;

        if (kk == 0) {
            int i0 = ic * 64;
            for (int j = tid; j < A_ROWS * 8; j += 256) {
                int r = j >> 3, c = j & 7;
                int t = t0 - 2 + r;
                float4 v0 = make_float4(0.f, 0.f, 0.f, 0.f);
                float4 v1 = v0;
                if ((unsigned)t < (unsigned)T_) {
                    const float4* p = (const float4*)(hb + (size_t)t * C_ + i0 + c * 8);
                    v0 = p[0]; v1 = p[1];
                }
                float vv[8] = {v0.x, v0.y, v0.z, v0.w, v1.x, v1.y, v1.z, v1.w};
                half8 hh, ll;
#pragma unroll
                for (int q = 0; q < 8; ++q) {
                    f16 x = (f16)vv[q];
                    hh[q] = x;
                    ll[q] = (f16)((vv[q] - (float)x) * LOSC);
                }
                int off = r * 64 + (c ^ (r & 7)) * 8;
                *(half8*)(Ahi + off) = hh;
                *(half8*)(Alo + off) = ll;
            }
            __syncthreads();
        }

        if (s + 1 < 80) issue_w(s + 1);

        half8 ah[4], al[4], bh[4], bl[4];
#pragma unroll
        for (int f = 0; f < 4; ++f) {
            int ar = wm * 64 + f * 16 + l15 + k;
            int aoff = ar * 64 + ((((sub << 2) | l4) ^ (ar & 7)) << 3);
            ah[f] = *(const half8*)(Ahi + aoff);
            al[f] = *(const half8*)(Alo + aoff);
            int wrow = l4 * 128 + wn * 64 + f * 16 + l15;
            bh[f] = *(const half8*)(Wb + (buf * 2 + 0) * WB_ARR_E + wrow * 8);
            bl[f] = *(const half8*)(Wb + (buf * 2 + 1) * WB_ARR_E + wrow * 8);
        }
        __builtin_amdgcn_s_setprio(1);
#pragma unroll
        for (int mf = 0; mf < 4; ++mf)
#pragma unroll
            for (int nf = 0; nf < 4; ++nf) {
                acc1[mf][nf] = __builtin_amdgcn_mfma_f32_16x16x32_f16(
                    ah[mf], bh[nf], acc1[mf][nf], 0, 0, 0);
                acc2[mf][nf] = __builtin_amdgcn_mfma_f32_16x16x32_f16(
                    al[mf], bh[nf], acc2[mf][nf], 0, 0, 0);
                acc2[mf][nf] = __builtin_amdgcn_mfma_f32_16x16x32_f16(
                    ah[mf], bl[nf], acc2[mf][nf], 0, 0, 0);
            }
        __builtin_amdgcn_s_setprio(0);
        __syncthreads();
    }

    float cb[4], lw[4];
#pragma unroll
    for (int nf = 0; nf < 4; ++nf) {
        int o = o0 + wn * 64 + nf * 16 + l15;
        cb[nf] = conv_b[o];
        lw[nf] = lin_w[o];
    }
    float* plb = pl + (size_t)(nb * 2 + wn) * (B_ * T_) + b * T_;
#pragma unroll
    for (int mf = 0; mf < 4; ++mf) {
#pragma unroll
        for (int reg = 0; reg < 4; ++reg) {
            float v = 0.f;
#pragma unroll
            for (int nf = 0; nf < 4; ++nf) {
                float c = acc1[mf][nf][reg] + acc2[mf][nf][reg] * (1.0f / LOSC);
                v += fmaxf(c + cb[nf], 0.f) * lw[nf];
            }
            v += __shfl_xor(v, 1);
            v += __shfl_xor(v, 2);
            v += __shfl_xor(v, 4);
            v += __shfl_xor(v, 8);
            int trow = t0 + wm * 64 + mf * 16 + l4 * 4 + reg;
            if (l15 == reg && trow < T_) plb[trow] = v;
        }
    }
}

// ---------------- combine partials + sigmoid -> alpha ----------------------
__global__ __launch_bounds__(256) void alpha_combine_kernel(
    const float* __restrict__ pl, const float* __restrict__ lin_b,
    float* __restrict__ alpha)
{
    int idx = blockIdx.x * 256 + threadIdx.x;
    if (idx >= B_ * T_) return;
    float s = lin_b[0];
#pragma unroll
    for (int p = 0; p < 8; ++p) s += pl[(size_t)p * (B_ * T_) + idx];
    alpha[idx] = 1.f / (1.f + expf(-s));
}

// ---------------- sequential CIF scan (exact fp32 ref semantics) -----------
__global__ __launch_bounds__(64) void scan_kernel(
    float* __restrict__ alpha, const int* __restrict__ mask,
    int2* __restrict__ seg_i, float2* __restrict__ seg_w,
    int* __restrict__ total_rows, float* __restrict__ out_loss)
{
    int lane = threadIdx.x;
    float lsum = 0.f;
    if (lane < B_) {
        const float4* ap = (const float4*)(alpha + lane * T_);
        const int4*   mp = (const int4*)(mask + lane * T_);
        float* astore = alpha + lane * T_;
        int2*   si = seg_i + lane * T_;
        float2* sw = seg_w + lane * T_;

        float acc = 0.f, leftover = 0.f;
        int nf = 0, prev_t = -1;

        float4 c0 = ap[0], c1 = ap[1];
        int4   m0 = mp[0], m1 = mp[1];
        for (int tc = 0; tc < T_ / 8; ++tc) {
            float4 n0, n1; int4 nm0, nm1;
            if (tc + 1 < T_ / 8) {
                n0 = ap[(tc + 1) * 2]; n1 = ap[(tc + 1) * 2 + 1];
                nm0 = mp[(tc + 1) * 2]; nm1 = mp[(tc + 1) * 2 + 1];
            }
            float av[8] = {c0.x, c0.y, c0.z, c0.w, c1.x, c1.y, c1.z, c1.w};
            int   mv[8] = {m0.x, m0.y, m0.z, m0.w, m1.x, m1.y, m1.z, m1.w};
#pragma unroll
            for (int u = 0; u < 8; ++u) {
                int t = tc * 8 + u;
                float araw = av[u];
                lsum += araw;
                float a = (mv[u] != 0) ? araw : 0.f;
                astore[t] = a;
                float acc2 = acc + a;
                float a1 = THf - acc;
                if (acc2 >= THf) {
                    si[nf] = make_int2(prev_t, t);
                    sw[nf] = make_float2(leftover, a1);
                    float rem = a - a1;
                    leftover = rem;
                    acc = rem;
                    prev_t = t;
                    ++nf;
                } else {
                    acc = acc2;
                }
            }
            c0 = n0; c1 = n1; m0 = nm0; m1 = nm1;
        }
        int tot = nf;
        if (acc >= 0.5f * THf) {
            si[nf] = make_int2(prev_t, T_);
            sw[nf] = make_float2(leftover, 0.f);
            ++tot;
        }
        total_rows[lane] = tot;
        lsum = fabsf(lsum);
    }
#pragma unroll
    for (int off = 16; off >= 1; off >>= 1) lsum += __shfl_down(lsum, off);
    if (lane == 0) out_loss[0] = lsum;
}

// ---------------- segmented weighted emission + zero fill ------------------
__global__ __launch_bounds__(128) void emit_kernel(
    const float* __restrict__ hs, const float* __restrict__ alpha,
    const int2* __restrict__ seg_i, const float2* __restrict__ seg_w,
    const int* __restrict__ total_rows, float* __restrict__ out)
{
    int blk = blockIdx.x;
    int b = blk / T_;
    int r = blk % T_;
    int tid = threadIdx.x;

    float4* cs4 = (float4*)(out + ((size_t)b * T_ + r) * C_);
    float* maskp = out + MASK_OFF + (size_t)b * T_ + r;
    int tot = total_rows[b];

    if (r >= tot) {
        float4 z; z.x = 0.f; z.y = 0.f; z.z = 0.f; z.w = 0.f;
        cs4[tid] = z;
        if (tid == 0) *maskp = 0.f;
        return;
    }
    int2   si = seg_i[b * T_ + r];
    float2 sw = seg_w[b * T_ + r];
    const float4* hb = (const float4*)(hs + (size_t)b * T_ * C_);
    const float*  ab = alpha + b * T_;

    float4 acc; acc.x = 0.f; acc.y = 0.f; acc.z = 0.f; acc.w = 0.f;
    int ts = si.x, te = si.y;
    if (ts >= 0) {
        float4 h = hb[(size_t)ts * (C_ / 4) + tid];
        acc.x = sw.x * h.x; acc.y = sw.x * h.y; acc.z = sw.x * h.z; acc.w = sw.x * h.w;
    }
    for (int t = ts + 1; t < te; ++t) {
        float a = ab[t];
        float4 h = hb[(size_t)t * (C_ / 4) + tid];
        acc.x = fmaf(a, h.x, acc.x); acc.y = fmaf(a, h.y, acc.y);
        acc.z = fmaf(a, h.z, acc.z); acc.w = fmaf(a, h.w, acc.w);
    }
    if (te < T_) {
        float4 h = hb[(size_t)te * (C_ / 4) + tid];
        acc.x = fmaf(sw.y, h.x, acc.x); acc.y = fmaf(sw.y, h.y, acc.y);
        acc.z = fmaf(sw.y, h.z, acc.z); acc.w = fmaf(sw.y, h.w, acc.w);
    }
    cs4[tid] = acc;
    if (tid == 0) *maskp = 1.f;
}

// ---------------- launch ---------------------------------------------------
extern "C" void kernel_launch(void* const* d_in, const int* in_sizes, int n_in,
                              void* d_out, int out_size, void* d_ws, size_t ws_size,
                              hipStream_t stream)
{
    const float* hs     = (const float*)d_in[0];
    const int*   hmask  = (const int*)d_in[1];
    const float* conv_w = (const float*)d_in[2];
    const float* conv_b = (const float*)d_in[3];
    const float* lin_w  = (const float*)d_in[4];
    const float* lin_b  = (const float*)d_in[5];
    float* out = (float*)d_out;
    char*  ws  = (char*)d_ws;

    if (ws_size >= (size_t)A_WS_NEED) {
        f16*    hs16  = (f16*)ws;
        f16*    whi   = (f16*)(ws + A_WHI_OFF);
        f16*    wlo   = (f16*)(ws + A_WLO_OFF);
        float*  pl    = (float*)(ws + A_PL_OFF);
        float*  alpha = (float*)(ws + A_ALPHA_OFF);
        int2*   seg_i = (int2*)(ws + A_SEGI_OFF);
        float2* seg_w = (float2*)(ws + A_SEGW_OFF);
        int*    tot   = (int*)(ws + A_TOT_OFF);

        w_prep_kernel<<<(512 * KW + 255) / 256, 256, 0, stream>>>(conv_w, whi, wlo);
        hs_split_kernel<<<(B_ * 16 * 3000 * 4 + 255) / 256, 256, 0, stream>>>(hs, hs16);
        conv_alpha_mfma_a<<<B_ * 24 * 4, 256, 0, stream>>>(hs16, whi, wlo, conv_b,
                                                           lin_w, pl);
        alpha_combine_kernel<<<(B_ * T_ + 255) / 256, 256, 0, stream>>>(pl, lin_b, alpha);
        scan_kernel<<<1, 64, 0, stream>>>(alpha, hmask, seg_i, seg_w, tot, out + LOSS_OFF);
        emit_kernel<<<B_ * T_, 128, 0, stream>>>(hs, alpha, seg_i, seg_w, tot, out);
    } else {
        f16*    whi   = (f16*)(ws + B_WHI_OFF);
        f16*    wlo   = (f16*)(ws + B_WLO_OFF);
        float*  pl    = (float*)(ws + B_PL_OFF);
        float*  alpha = (float*)(ws + B_ALPHA_OFF);
        int2*   seg_i = (int2*)(ws + B_SEGI_OFF);
        float2* seg_w = (float2*)(ws + B_SEGW_OFF);
        int*    tot   = (int*)(ws + B_TOT_OFF);

        w_prep_kernel<<<(512 * KW + 255) / 256, 256, 0, stream>>>(conv_w, whi, wlo);
        conv_alpha_mfma_b<<<B_ * 24 * 4, 256, 0, stream>>>(hs, whi, wlo, conv_b,
                                                           lin_w, pl);
        alpha_combine_kernel<<<(B_ * T_ + 255) / 256, 256, 0, stream>>>(pl, lin_b, alpha);
        scan_kernel<<<1, 64, 0, stream>>>(alpha, hmask, seg_i, seg_w, tot, out + LOSS_OFF);
        emit_kernel<<<B_ * T_, 128, 0, stream>>>(hs, alpha, seg_i, seg_w, tot, out);
    }
}

// Round 8
// 999.542 us; speedup vs baseline: 1.1736x; 1.1736x over previous
//
#include <hip/hip_runtime.h>
#include <math.h>

#define B_ 32
#define T_ 3000
#define C_ 512
#define THf 1.0f
#define KW 2560   // 5*512 flattened conv K

typedef _Float16 f16;
typedef _Float16 half8 __attribute__((ext_vector_type(8)));
typedef float floatx4 __attribute__((ext_vector_type(4)));

#define GLOBAL_AS __attribute__((address_space(1)))
#define LDS_AS __attribute__((address_space(3)))

#define CS_SIZE  ((size_t)B_ * T_ * C_)
#define MASK_OFF CS_SIZE
#define LOSS_OFF (CS_SIZE + (size_t)B_ * T_)

// lo-part scale: 2^6 (keeps lo parts f16-normal; /64 is exact in f16)
#define LOSC 64.0f

// ================= PATH A ws layout (needs ~207 MB) ========================
// hs16 [b][ic32][t][64 f16] (32 hi + 32 lo64, 16B-chunks slot-swizzled by (t+2)&7)
#define HS16_ELEMS   ((size_t)B_ * 16 * 3000 * 64)      // 98,304,000 f16
#define HS16_ZEL     HS16_ELEMS                          // 64-f16 zero row
#define HS16_BYTES   (2 * (HS16_ELEMS + 64))             // 196,608,128
#define A_WHI_OFF    HS16_BYTES
#define A_WLO_OFF    (A_WHI_OFF + 2621440)
#define A_PL_OFF     (A_WLO_OFF + 2621440)
#define A_ALPHA_OFF  (A_PL_OFF + 3072000)
#define A_SEGI_OFF   (A_ALPHA_OFF + 384000)
#define A_SEGW_OFF   (A_SEGI_OFF + 768000)
#define A_TOT_OFF    (A_SEGW_OFF + 768000)
#define A_WS_NEED    (A_TOT_OFF + 128)

// ================= PATH B ws layout (fallback, ~10 MB) =====================
#define B_WHI_OFF   0
#define B_WLO_OFF   2621440
#define B_PL_OFF    5242880
#define B_ALPHA_OFF 8314880
#define B_SEGI_OFF  8698880
#define B_SEGW_OFF  9466880
#define B_TOT_OFF   10234880

// ---------------- W prep: [o][i][k] fp32 -> [k][i8][o][ie] f16 hi/lo64 -----
__global__ __launch_bounds__(256) void w_prep_kernel(
    const float* __restrict__ W, f16* __restrict__ whi, f16* __restrict__ wlo)
{
    int idx = blockIdx.x * 256 + threadIdx.x;
    if (idx >= 512 * KW) return;
    int ie = idx & 7;
    int o  = (idx >> 3) & 511;
    int i8 = (idx >> 12) & 63;
    int k  = idx >> 18;
    int i  = i8 * 8 + ie;
    float w = W[o * KW + i * 5 + k];
    f16 h = (f16)w;
    whi[idx] = h;
    wlo[idx] = (f16)((w - (float)h) * LOSC);
}

// ---------------- hs split: fp32 -> hi/lo64 f16, chunk-swizzled, vectorized
__global__ __launch_bounds__(256) void hs_split_kernel(
    const float* __restrict__ hs, f16* __restrict__ hs16)
{
    int idx = blockIdx.x * 256 + threadIdx.x;   // < 32*16*3000*4 = 6,144,000
    if (idx < 8) {
        half8 z = {(f16)0.f, (f16)0.f, (f16)0.f, (f16)0.f,
                   (f16)0.f, (f16)0.f, (f16)0.f, (f16)0.f};
        *(half8*)(hs16 + HS16_ZEL + idx * 8) = z;
    }
    if (idx >= B_ * 16 * 3000 * 4) return;
    int ch  = idx & 3;
    int row = idx >> 2;
    int t   = row % 3000;
    int bic = row / 3000;
    int b   = bic >> 4;
    int ic  = bic & 15;
    const float* src = hs + ((size_t)b * 3000 + t) * 512 + ic * 32 + ch * 8;
    float4 v0 = *(const float4*)src;
    float4 v1 = *(const float4*)(src + 4);
    float vv[8] = {v0.x, v0.y, v0.z, v0.w, v1.x, v1.y, v1.z, v1.w};
    half8 hh, ll;
#pragma unroll
    for (int q = 0; q < 8; ++q) {
        f16 x = (f16)vv[q];
        hh[q] = x;
        ll[q] = (f16)((vv[q] - (float)x) * LOSC);
    }
    int m7 = (t + 2) & 7;
    size_t rb = (size_t)row * 64;
    *(half8*)(hs16 + rb + (size_t)((ch ^ m7) * 8))       = hh;
    *(half8*)(hs16 + rb + (size_t)(((ch + 4) ^ m7) * 8)) = ll;
}

// ---------------- PATH A conv: 16x16x32 MFMA, single acc, 3 blocks/CU ------
// block 128t x 128o, 4 waves (2m x 2n) of 64x64; K=32/step, 80 steps.
// LDS f16 units: A[8704] @0 (136 rows x 64, single-buffered),
//                W @8704: [buf 2][arr(hi/lo) 2][4096]  (kc 4 x o 128 x ie 8)
__global__ __launch_bounds__(256, 3) void conv_alpha_mfma_a(
    const f16* __restrict__ hs16, const f16* __restrict__ whi_g,
    const f16* __restrict__ wlo_g, const float* __restrict__ conv_b,
    const float* __restrict__ lin_w, float* __restrict__ pl)
{
    __shared__ f16 sm[25088];   // 50,176 B -> 3 blocks/CU

    int tid = threadIdx.x;
    int bid = blockIdx.x;
    int nb  = bid & 3;
    int mtg = bid >> 2;
    int b   = mtg / 24;
    int mt  = mtg - b * 24;
    int t0  = mt * 128;

    int wid = tid >> 6, l = tid & 63;
    int wm = wid >> 1, wn = wid & 1;
    int l15 = l & 15, l4 = l >> 4;
    int o0 = nb * 128;

    floatx4 acc[4][4];
#pragma unroll
    for (int mf = 0; mf < 4; ++mf)
#pragma unroll
        for (int nf = 0; nf < 4; ++nf) acc[mf][nf] = (floatx4)0.f;

    // async A tile (single buffer): 17 x 1KB (5 instrs/wave, last duplicated)
    auto issue_a = [&](int icn) {
        const f16* hbase = hs16 + ((size_t)(b * 16 + icn)) * 3000 * 64;
        f16* abase = sm;
#pragma unroll
        for (int jj = 0; jj < 4; ++jj) {
            int j = wid + jj * 4;
            int r = j * 8 + (l >> 3);
            int t = t0 - 2 + r;
            const f16* gsrc = ((unsigned)t < 3000u)
                ? hbase + (size_t)t * 64 + (l & 7) * 8
                : hs16 + HS16_ZEL + (l & 7) * 8;
            __builtin_amdgcn_global_load_lds((const GLOBAL_AS void*)gsrc,
                                             (LDS_AS void*)(abase + j * 512), 16, 0, 0);
        }
        {
            int j = (wid == 0) ? 16 : (wid + 12);
            int r = j * 8 + (l >> 3);
            int t = t0 - 2 + r;
            const f16* gsrc = ((unsigned)t < 3000u)
                ? hbase + (size_t)t * 64 + (l & 7) * 8
                : hs16 + HS16_ZEL + (l & 7) * 8;
            __builtin_amdgcn_global_load_lds((const GLOBAL_AS void*)gsrc,
                                             (LDS_AS void*)(abase + j * 512), 16, 0, 0);
        }
    };
    // async W tile: step s = ic*5+k -> 16 x 1KB regions (4 instrs/wave)
    auto issue_w = [&](int s2) {
        int buf = s2 & 1;
        int ic2 = s2 / 5, k2 = s2 - ic2 * 5;
#pragma unroll
        for (int rr = 0; rr < 4; ++rr) {
            int r = wid * 4 + rr;
            int arr = r >> 3, kc = (r >> 1) & 3, oh = r & 1;
            const f16* gsrc = (arr ? wlo_g : whi_g) +
                ((size_t)((k2 * 64 + ic2 * 4 + kc) * 512 + o0 + oh * 64 + l)) * 8;
            f16* ldst = sm + 8704 + (buf * 2 + arr) * 4096 + (kc * 128 + oh * 64) * 8;
            __builtin_amdgcn_global_load_lds((const GLOBAL_AS void*)gsrc,
                                             (LDS_AS void*)ldst, 16, 0, 0);
        }
    };

    issue_a(0);
    issue_w(0);
    __syncthreads();

    const f16 inv64 = (f16)0.015625f;

    for (int s = 0; s < 80; ++s) {
        int ic = s / 5, k = s - ic * 5;
        int wbuf = s & 1;
        bool aStep = (k == 4);

        if (!aStep && s + 1 < 80) issue_w(s + 1);

        const f16* Ab = sm;
        const f16* Wh = sm + 8704 + (wbuf * 2 + 0) * 4096;
        const f16* Wl = sm + 8704 + (wbuf * 2 + 1) * 4096;
        int m7 = (l15 + k) & 7;
        int sh = (l4 ^ m7) * 8;
        int sl = ((l4 + 4) ^ m7) * 8;

        // W fragments stay resident (reused by all 4 mf); A frags per-mf.
        half8 bh[4], bl[4];
#pragma unroll
        for (int f = 0; f < 4; ++f) {
            int wrow = l4 * 128 + wn * 64 + f * 16 + l15;
            bh[f] = *(const half8*)(Wh + wrow * 8);
            bl[f] = *(const half8*)(Wl + wrow * 8);
        }

        __builtin_amdgcn_s_setprio(1);
#pragma unroll
        for (int mf = 0; mf < 4; ++mf) {
            int r = wm * 64 + mf * 16 + l15 + k;
            half8 ah = *(const half8*)(Ab + r * 64 + sh);
            half8 al = *(const half8*)(Ab + r * 64 + sl);
            half8 ahd = ah * inv64;   // ah/64 (exact)
            half8 ald = al * inv64;   // true a-lo (al64/64, exact)
#pragma unroll
            for (int nf = 0; nf < 4; ++nf) {
                acc[mf][nf] = __builtin_amdgcn_mfma_f32_16x16x32_f16(
                    ah, bh[nf], acc[mf][nf], 0, 0, 0);
                acc[mf][nf] = __builtin_amdgcn_mfma_f32_16x16x32_f16(
                    ald, bh[nf], acc[mf][nf], 0, 0, 0);
                acc[mf][nf] = __builtin_amdgcn_mfma_f32_16x16x32_f16(
                    ahd, bl[nf], acc[mf][nf], 0, 0, 0);
            }
        }
        __builtin_amdgcn_s_setprio(0);

        if (aStep) {
            __syncthreads();                 // all waves done reading A tile ic
            if (ic + 1 < 16) issue_a(ic + 1);
            if (s + 1 < 80) issue_w(s + 1);
            __syncthreads();                 // drain -> new A + W landed
        } else {
            __syncthreads();
        }
    }

    // epilogue: relu(c+cb)*lw, reduce over o (16 lanes), scatter rows
    float cb[4], lw[4];
#pragma unroll
    for (int nf = 0; nf < 4; ++nf) {
        int o = o0 + wn * 64 + nf * 16 + l15;
        cb[nf] = conv_b[o];
        lw[nf] = lin_w[o];
    }
    float* plb = pl + (size_t)(nb * 2 + wn) * (B_ * T_) + b * T_;
#pragma unroll
    for (int mf = 0; mf < 4; ++mf) {
#pragma unroll
        for (int reg = 0; reg < 4; ++reg) {
            float v = 0.f;
#pragma unroll
            for (int nf = 0; nf < 4; ++nf) {
                float c = acc[mf][nf][reg];
                v += fmaxf(c + cb[nf], 0.f) * lw[nf];
            }
            v += __shfl_xor(v, 1);
            v += __shfl_xor(v, 2);
            v += __shfl_xor(v, 4);
            v += __shfl_xor(v, 8);
            int trow = t0 + wm * 64 + mf * 16 + l4 * 4 + reg;
            if (l15 == reg && trow < T_) plb[trow] = v;
        }
    }
}

// ---------------- PATH B conv (fallback, 16x16x32, in-kernel conversion) ---
#define A_ROWS 132
#define ALO_OFF_E  8448
#define WB_OFF_E   16896
#define WB_ARR_E   4096

__global__ __launch_bounds__(256, 2) void conv_alpha_mfma_b(
    const float* __restrict__ hs, const f16* __restrict__ whi_g,
    const f16* __restrict__ wlo_g, const float* __restrict__ conv_b,
    const float* __restrict__ lin_w, float* __restrict__ pl)
{
    __shared__ f16 sm[33280];
    f16* Ahi = sm;
    f16* Alo = sm + ALO_OFF_E;
    f16* Wb  = sm + WB_OFF_E;

    int tid = threadIdx.x;
    int bid = blockIdx.x;
    int nb  = bid & 3;
    int mtg = bid >> 2;
    int b   = mtg / 24;
    int mt  = mtg - b * 24;
    int t0  = mt * 128;

    int wid = tid >> 6, l = tid & 63;
    int wm = wid >> 1, wn = wid & 1;
    int l15 = l & 15, l4 = l >> 4;

    const float* hb = hs + (size_t)b * T_ * C_;
    int o0 = nb * 128;

    floatx4 acc1[4][4], acc2[4][4];
#pragma unroll
    for (int mf = 0; mf < 4; ++mf)
#pragma unroll
        for (int nf = 0; nf < 4; ++nf) {
            acc1[mf][nf] = (floatx4)0.f;
            acc2[mf][nf] = (floatx4)0.f;
        }

    auto issue_w = [&](int s2) {
        int buf = s2 & 1;
        int ic2 = s2 / 10, kk2 = s2 % 10;
        int k2 = kk2 >> 1, sub2 = kk2 & 1;
        int i8b = ic2 * 8 + sub2 * 4;
#pragma unroll
        for (int rr = 0; rr < 4; ++rr) {
            int r = wid * 4 + rr;
            int arr = r >> 3, kc = (r >> 1) & 3, oh = r & 1;
            const f16* gsrc = (arr ? wlo_g : whi_g) +
                ((size_t)((k2 * 64 + i8b + kc) * 512 + o0 + oh * 64 + l)) * 8;
            f16* ldst = Wb + (buf * 2 + arr) * WB_ARR_E + (kc * 128 + oh * 64) * 8;
            __builtin_amdgcn_global_load_lds((const GLOBAL_AS void*)gsrc,
                                             (LDS_AS void*)ldst, 16, 0, 0);
        }
    };

    issue_w(0);

    for (int s = 0; s < 80; ++s) {
        int ic = s / 10, kk = s % 10;
        int k = kk >> 1, sub = kk & 1;
        int buf = s & 1;

        if (kk == 0) {
            int i0 = ic * 64;
            for (int j = tid; j < A_ROWS * 8; j += 256) {
                int r = j >> 3, c = j & 7;
                int t = t0 - 2 + r;
                float4 v0 = make_float4(0.f, 0.f, 0.f, 0.f);
                float4 v1 = v0;
                if ((unsigned)t < (unsigned)T_) {
                    const float4* p = (const float4*)(hb + (size_t)t * C_ + i0 + c * 8);
                    v0 = p[0]; v1 = p[1];
                }
                float vv[8] = {v0.x, v0.y, v0.z, v0.w, v1.x, v1.y, v1.z, v1.w};
                half8 hh, ll;
#pragma unroll
                for (int q = 0; q < 8; ++q) {
                    f16 x = (f16)vv[q];
                    hh[q] = x;
                    ll[q] = (f16)((vv[q] - (float)x) * LOSC);
                }
                int off = r * 64 + (c ^ (r & 7)) * 8;
                *(half8*)(Ahi + off) = hh;
                *(half8*)(Alo + off) = ll;
            }
            __syncthreads();
        }

        if (s + 1 < 80) issue_w(s + 1);

        half8 ah[4], al[4], bh[4], bl[4];
#pragma unroll
        for (int f = 0; f < 4; ++f) {
            int ar = wm * 64 + f * 16 + l15 + k;
            int aoff = ar * 64 + ((((sub << 2) | l4) ^ (ar & 7)) << 3);
            ah[f] = *(const half8*)(Ahi + aoff);
            al[f] = *(const half8*)(Alo + aoff);
            int wrow = l4 * 128 + wn * 64 + f * 16 + l15;
            bh[f] = *(const half8*)(Wb + (buf * 2 + 0) * WB_ARR_E + wrow * 8);
            bl[f] = *(const half8*)(Wb + (buf * 2 + 1) * WB_ARR_E + wrow * 8);
        }
        __builtin_amdgcn_s_setprio(1);
#pragma unroll
        for (int mf = 0; mf < 4; ++mf)
#pragma unroll
            for (int nf = 0; nf < 4; ++nf) {
                acc1[mf][nf] = __builtin_amdgcn_mfma_f32_16x16x32_f16(
                    ah[mf], bh[nf], acc1[mf][nf], 0, 0, 0);
                acc2[mf][nf] = __builtin_amdgcn_mfma_f32_16x16x32_f16(
                    al[mf], bh[nf], acc2[mf][nf], 0, 0, 0);
                acc2[mf][nf] = __builtin_amdgcn_mfma_f32_16x16x32_f16(
                    ah[mf], bl[nf], acc2[mf][nf], 0, 0, 0);
            }
        __builtin_amdgcn_s_setprio(0);
        __syncthreads();
    }

    float cb[4], lw[4];
#pragma unroll
    for (int nf = 0; nf < 4; ++nf) {
        int o = o0 + wn * 64 + nf * 16 + l15;
        cb[nf] = conv_b[o];
        lw[nf] = lin_w[o];
    }
    float* plb = pl + (size_t)(nb * 2 + wn) * (B_ * T_) + b * T_;
#pragma unroll
    for (int mf = 0; mf < 4; ++mf) {
#pragma unroll
        for (int reg = 0; reg < 4; ++reg) {
            float v = 0.f;
#pragma unroll
            for (int nf = 0; nf < 4; ++nf) {
                float c = acc1[mf][nf][reg] + acc2[mf][nf][reg] * (1.0f / LOSC);
                v += fmaxf(c + cb[nf], 0.f) * lw[nf];
            }
            v += __shfl_xor(v, 1);
            v += __shfl_xor(v, 2);
            v += __shfl_xor(v, 4);
            v += __shfl_xor(v, 8);
            int trow = t0 + wm * 64 + mf * 16 + l4 * 4 + reg;
            if (l15 == reg && trow < T_) plb[trow] = v;
        }
    }
}

// ---------------- combine partials + sigmoid -> alpha ----------------------
__global__ __launch_bounds__(256) void alpha_combine_kernel(
    const float* __restrict__ pl, const float* __restrict__ lin_b,
    float* __restrict__ alpha)
{
    int idx = blockIdx.x * 256 + threadIdx.x;
    if (idx >= B_ * T_) return;
    float s = lin_b[0];
#pragma unroll
    for (int p = 0; p < 8; ++p) s += pl[(size_t)p * (B_ * T_) + idx];
    alpha[idx] = 1.f / (1.f + expf(-s));
}

// ---------------- sequential CIF scan (exact fp32 ref semantics) -----------
__global__ __launch_bounds__(64) void scan_kernel(
    float* __restrict__ alpha, const int* __restrict__ mask,
    int2* __restrict__ seg_i, float2* __restrict__ seg_w,
    int* __restrict__ total_rows, float* __restrict__ out_loss)
{
    int lane = threadIdx.x;
    float lsum = 0.f;
    if (lane < B_) {
        const float4* ap = (const float4*)(alpha + lane * T_);
        const int4*   mp = (const int4*)(mask + lane * T_);
        float* astore = alpha + lane * T_;
        int2*   si = seg_i + lane * T_;
        float2* sw = seg_w + lane * T_;

        float acc = 0.f, leftover = 0.f;
        int nf = 0, prev_t = -1;

        float4 c0 = ap[0], c1 = ap[1];
        int4   m0 = mp[0], m1 = mp[1];
        for (int tc = 0; tc < T_ / 8; ++tc) {
            float4 n0, n1; int4 nm0, nm1;
            if (tc + 1 < T_ / 8) {
                n0 = ap[(tc + 1) * 2]; n1 = ap[(tc + 1) * 2 + 1];
                nm0 = mp[(tc + 1) * 2]; nm1 = mp[(tc + 1) * 2 + 1];
            }
            float av[8] = {c0.x, c0.y, c0.z, c0.w, c1.x, c1.y, c1.z, c1.w};
            int   mv[8] = {m0.x, m0.y, m0.z, m0.w, m1.x, m1.y, m1.z, m1.w};
#pragma unroll
            for (int u = 0; u < 8; ++u) {
                int t = tc * 8 + u;
                float araw = av[u];
                lsum += araw;
                float a = (mv[u] != 0) ? araw : 0.f;
                astore[t] = a;
                float acc2 = acc + a;
                float a1 = THf - acc;
                if (acc2 >= THf) {
                    si[nf] = make_int2(prev_t, t);
                    sw[nf] = make_float2(leftover, a1);
                    float rem = a - a1;
                    leftover = rem;
                    acc = rem;
                    prev_t = t;
                    ++nf;
                } else {
                    acc = acc2;
                }
            }
            c0 = n0; c1 = n1; m0 = nm0; m1 = nm1;
        }
        int tot = nf;
        if (acc >= 0.5f * THf) {
            si[nf] = make_int2(prev_t, T_);
            sw[nf] = make_float2(leftover, 0.f);
            ++tot;
        }
        total_rows[lane] = tot;
        lsum = fabsf(lsum);
    }
#pragma unroll
    for (int off = 16; off >= 1; off >>= 1) lsum += __shfl_down(lsum, off);
    if (lane == 0) out_loss[0] = lsum;
}

// ---------------- segmented weighted emission + zero fill ------------------
__global__ __launch_bounds__(128) void emit_kernel(
    const float* __restrict__ hs, const float* __restrict__ alpha,
    const int2* __restrict__ seg_i, const float2* __restrict__ seg_w,
    const int* __restrict__ total_rows, float* __restrict__ out)
{
    int blk = blockIdx.x;
    int b = blk / T_;
    int r = blk % T_;
    int tid = threadIdx.x;

    float4* cs4 = (float4*)(out + ((size_t)b * T_ + r) * C_);
    float* maskp = out + MASK_OFF + (size_t)b * T_ + r;
    int tot = total_rows[b];

    if (r >= tot) {
        float4 z; z.x = 0.f; z.y = 0.f; z.z = 0.f; z.w = 0.f;
        cs4[tid] = z;
        if (tid == 0) *maskp = 0.f;
        return;
    }
    int2   si = seg_i[b * T_ + r];
    float2 sw = seg_w[b * T_ + r];
    const float4* hb = (const float4*)(hs + (size_t)b * T_ * C_);
    const float*  ab = alpha + b * T_;

    float4 acc; acc.x = 0.f; acc.y = 0.f; acc.z = 0.f; acc.w = 0.f;
    int ts = si.x, te = si.y;
    if (ts >= 0) {
        float4 h = hb[(size_t)ts * (C_ / 4) + tid];
        acc.x = sw.x * h.x; acc.y = sw.x * h.y; acc.z = sw.x * h.z; acc.w = sw.x * h.w;
    }
    for (int t = ts + 1; t < te; ++t) {
        float a = ab[t];
        float4 h = hb[(size_t)t * (C_ / 4) + tid];
        acc.x = fmaf(a, h.x, acc.x); acc.y = fmaf(a, h.y, acc.y);
        acc.z = fmaf(a, h.z, acc.z); acc.w = fmaf(a, h.w, acc.w);
    }
    if (te < T_) {
        float4 h = hb[(size_t)te * (C_ / 4) + tid];
        acc.x = fmaf(sw.y, h.x, acc.x); acc.y = fmaf(sw.y, h.y, acc.y);
        acc.z = fmaf(sw.y, h.z, acc.z); acc.w = fmaf(sw.y, h.w, acc.w);
    }
    cs4[tid] = acc;
    if (tid == 0) *maskp = 1.f;
}

// ---------------- launch ---------------------------------------------------
extern "C" void kernel_launch(void* const* d_in, const int* in_sizes, int n_in,
                              void* d_out, int out_size, void* d_ws, size_t ws_size,
                              hipStream_t stream)
{
    const float* hs     = (const float*)d_in[0];
    const int*   hmask  = (const int*)d_in[1];
    const float* conv_w = (const float*)d_in[2];
    const float* conv_b = (const float*)d_in[3];
    const float* lin_w  = (const float*)d_in[4];
    const float* lin_b  = (const float*)d_in[5];
    float* out = (float*)d_out;
    char*  ws  = (char*)d_ws;

    if (ws_size >= (size_t)A_WS_NEED) {
        f16*    hs16  = (f16*)ws;
        f16*    whi   = (f16*)(ws + A_WHI_OFF);
        f16*    wlo   = (f16*)(ws + A_WLO_OFF);
        float*  pl    = (float*)(ws + A_PL_OFF);
        float*  alpha = (float*)(ws + A_ALPHA_OFF);
        int2*   seg_i = (int2*)(ws + A_SEGI_OFF);
        float2* seg_w = (float2*)(ws + A_SEGW_OFF);
        int*    tot   = (int*)(ws + A_TOT_OFF);

        w_prep_kernel<<<(512 * KW + 255) / 256, 256, 0, stream>>>(conv_w, whi, wlo);
        hs_split_kernel<<<(B_ * 16 * 3000 * 4 + 255) / 256, 256, 0, stream>>>(hs, hs16);
        conv_alpha_mfma_a<<<B_ * 24 * 4, 256, 0, stream>>>(hs16, whi, wlo, conv_b,
                                                           lin_w, pl);
        alpha_combine_kernel<<<(B_ * T_ + 255) / 256, 256, 0, stream>>>(pl, lin_b, alpha);
        scan_kernel<<<1, 64, 0, stream>>>(alpha, hmask, seg_i, seg_w, tot, out + LOSS_OFF);
        emit_kernel<<<B_ * T_, 128, 0, stream>>>(hs, alpha, seg_i, seg_w, tot, out);
    } else {
        f16*    whi   = (f16*)(ws + B_WHI_OFF);
        f16*    wlo   = (f16*)(ws + B_WLO_OFF);
        float*  pl    = (float*)(ws + B_PL_OFF);
        float*  alpha = (float*)(ws + B_ALPHA_OFF);
        int2*   seg_i = (int2*)(ws + B_SEGI_OFF);
        float2* seg_w = (float2*)(ws + B_SEGW_OFF);
        int*    tot   = (int*)(ws + B_TOT_OFF);

        w_prep_kernel<<<(512 * KW + 255) / 256, 256, 0, stream>>>(conv_w, whi, wlo);
        conv_alpha_mfma_b<<<B_ * 24 * 4, 256, 0, stream>>>(hs, whi, wlo, conv_b,
                                                           lin_w, pl);
        alpha_combine_kernel<<<(B_ * T_ + 255) / 256, 256, 0, stream>>>(pl, lin_b, alpha);
        scan_kernel<<<1, 64, 0, stream>>>(alpha, hmask, seg_i, seg_w, tot, out + LOSS_OFF);
        emit_kernel<<<B_ * T_, 128, 0, stream>>>(hs, alpha, seg_i, seg_w, tot, out);
    }
}

// Round 9
// 991.850 us; speedup vs baseline: 1.1827x; 1.0078x over previous
//
#include <hip/hip_runtime.h>
#include <math.h>

#define B_ 32
#define T_ 3000
#define C_ 512
#define THf 1.0f
#define KW 2560   // 5*512 flattened conv K

typedef _Float16 f16;
typedef _Float16 half8 __attribute__((ext_vector_type(8)));
typedef float floatx4 __attribute__((ext_vector_type(4)));

#define GLOBAL_AS __attribute__((address_space(1)))
#define LDS_AS __attribute__((address_space(3)))

#define CS_SIZE  ((size_t)B_ * T_ * C_)
#define MASK_OFF CS_SIZE
#define LOSS_OFF (CS_SIZE + (size_t)B_ * T_)

#define LOSC 64.0f   // lo-part scale 2^6

// ================= PATH A ws layout (needs ~207 MB) ========================
#define HS16_ELEMS   ((size_t)B_ * 16 * 3000 * 64)
#define HS16_ZEL     HS16_ELEMS
#define HS16_BYTES   (2 * (HS16_ELEMS + 64))
#define A_WHI_OFF    HS16_BYTES
#define A_WLO_OFF    (A_WHI_OFF + 2621440)
#define A_PL_OFF     (A_WLO_OFF + 2621440)
#define A_ALPHA_OFF  (A_PL_OFF + 3072000)
#define A_SEGI_OFF   (A_ALPHA_OFF + 384000)
#define A_SEGW_OFF   (A_SEGI_OFF + 768000)
#define A_TOT_OFF    (A_SEGW_OFF + 768000)
#define A_WS_NEED    (A_TOT_OFF + 128)

// ================= PATH B ws layout (fallback, ~10 MB) =====================
#define B_WHI_OFF   0
#define B_WLO_OFF   2621440
#define B_PL_OFF    5242880
#define B_ALPHA_OFF 8314880
#define B_SEGI_OFF  8698880
#define B_SEGW_OFF  9466880
#define B_TOT_OFF   10234880

#define NB_HS 24000   // hs-split blocks (32*16*3000*4 / 256)
#define NB_W  5120    // w-prep blocks (512*2560 / 256)

// ------- fused prep: hs fp32 -> hi/lo64 f16 swizzled; W -> [k][i8][o][ie] ---
__global__ __launch_bounds__(256) void prep_kernel(
    const float* __restrict__ hs, f16* __restrict__ hs16,
    const float* __restrict__ W, f16* __restrict__ whi, f16* __restrict__ wlo)
{
    int blk = blockIdx.x;
    if (blk < NB_HS) {
        int idx = blk * 256 + threadIdx.x;
        if (idx < 8) {
            half8 z = {(f16)0.f, (f16)0.f, (f16)0.f, (f16)0.f,
                       (f16)0.f, (f16)0.f, (f16)0.f, (f16)0.f};
            *(half8*)(hs16 + HS16_ZEL + idx * 8) = z;
        }
        int ch  = idx & 3;
        int row = idx >> 2;
        int t   = row % 3000;
        int bic = row / 3000;
        int b   = bic >> 4;
        int ic  = bic & 15;
        const float* src = hs + ((size_t)b * 3000 + t) * 512 + ic * 32 + ch * 8;
        float4 v0 = *(const float4*)src;
        float4 v1 = *(const float4*)(src + 4);
        float vv[8] = {v0.x, v0.y, v0.z, v0.w, v1.x, v1.y, v1.z, v1.w};
        half8 hh, ll;
#pragma unroll
        for (int q = 0; q < 8; ++q) {
            f16 x = (f16)vv[q];
            hh[q] = x;
            ll[q] = (f16)((vv[q] - (float)x) * LOSC);
        }
        int m7 = (t + 2) & 7;
        size_t rb = (size_t)row * 64;
        *(half8*)(hs16 + rb + (size_t)((ch ^ m7) * 8))       = hh;
        *(half8*)(hs16 + rb + (size_t)(((ch + 4) ^ m7) * 8)) = ll;
    } else {
        int idx = (blk - NB_HS) * 256 + threadIdx.x;
        if (idx >= 512 * KW) return;
        int ie = idx & 7;
        int o  = (idx >> 3) & 511;
        int i8 = (idx >> 12) & 63;
        int k  = idx >> 18;
        int i  = i8 * 8 + ie;
        float w = W[o * KW + i * 5 + k];
        f16 h = (f16)w;
        whi[idx] = h;
        wlo[idx] = (f16)((w - (float)h) * LOSC);
    }
}

// ---------------- PATH A conv: W-in-regs, A-dbuf, barrier per 5 steps ------
// block 128t x 128o, 4 waves (2m x 2n) of 64x64; K=32/step, 80 steps.
// LDS: A dbuf 2 x 8704 f16 = 34,816 B. W: register double-buffer.
__global__ __launch_bounds__(256, 2) void conv_alpha_mfma_a(
    const f16* __restrict__ hs16, const f16* __restrict__ whi_g,
    const f16* __restrict__ wlo_g, const float* __restrict__ conv_b,
    const float* __restrict__ lin_w, float* __restrict__ pl)
{
    __shared__ f16 sm[2][8704];

    int tid  = threadIdx.x;
    int orig = blockIdx.x;
    int bid  = (orig & 7) * 384 + (orig >> 3);   // XCD-chunk swizzle (3072%8==0)
    int nb  = bid & 3;
    int mtg = bid >> 2;
    int b   = mtg / 24;
    int mt  = mtg - b * 24;
    int t0  = mt * 128;

    int wid = tid >> 6, l = tid & 63;
    int wm = wid >> 1, wn = wid & 1;
    int l15 = l & 15, l4 = l >> 4;
    int o0 = nb * 128;

    floatx4 acc[4][4];
#pragma unroll
    for (int mf = 0; mf < 4; ++mf)
#pragma unroll
        for (int nf = 0; nf < 4; ++nf) acc[mf][nf] = (floatx4)0.f;

    // async A tile into sm[abuf]: 17 x 1KB (5 instrs/wave, last duplicated)
    auto issue_a = [&](int icn, int abuf) {
        const f16* hbase = hs16 + ((size_t)(b * 16 + icn)) * 3000 * 64;
        f16* abase = &sm[abuf][0];
#pragma unroll
        for (int jj = 0; jj < 4; ++jj) {
            int j = wid + jj * 4;
            int r = j * 8 + (l >> 3);
            int t = t0 - 2 + r;
            const f16* gsrc = ((unsigned)t < 3000u)
                ? hbase + (size_t)t * 64 + (l & 7) * 8
                : hs16 + HS16_ZEL + (l & 7) * 8;
            __builtin_amdgcn_global_load_lds((const GLOBAL_AS void*)gsrc,
                                             (LDS_AS void*)(abase + j * 512), 16, 0, 0);
        }
        {
            int j = (wid == 0) ? 16 : (wid + 12);
            int r = j * 8 + (l >> 3);
            int t = t0 - 2 + r;
            const f16* gsrc = ((unsigned)t < 3000u)
                ? hbase + (size_t)t * 64 + (l & 7) * 8
                : hs16 + HS16_ZEL + (l & 7) * 8;
            __builtin_amdgcn_global_load_lds((const GLOBAL_AS void*)gsrc,
                                             (LDS_AS void*)(abase + j * 512), 16, 0, 0);
        }
    };

    // per-lane W base (elements): covers (l4 -> i8 sub, o-lane)
    const f16* whiL = whi_g + ((l4 * 512) + o0 + wn * 64 + l15) * 8;
    const f16* wloL = wlo_g + ((l4 * 512) + o0 + wn * 64 + l15) * 8;

    const f16 inv64 = (f16)0.015625f;

    half8 bhA[4], blA[4], bhB[4], blB[4];

    // prologue: stage A(0) into buf0; load W(step 0) into set A
    issue_a(0, 0);
#pragma unroll
    for (int nf = 0; nf < 4; ++nf) {
        bhA[nf] = *(const half8*)(whiL + nf * 128);
        blA[nf] = *(const half8*)(wloL + nf * 128);
    }
    __syncthreads();

#define CONV_STEP(KK, BHC, BLC, BHN, BLN)                                     \
    do {                                                                      \
        const int kk_ = (KK);                                                 \
        const int kcur_ = kk_ % 5;                                            \
        const int bufc_ = (kk_ < 5) ? 0 : 1;                                  \
        if (kk_ == 0) issue_a(icB, 1);                                        \
        if (kk_ == 5) issue_a((icA + 2 <= 15) ? icA + 2 : 15, 0);             \
        {                                                                     \
            int nic_ = (kk_ + 1 < 5) ? icA                                    \
                       : ((kk_ + 1 < 10) ? icB                                \
                                         : ((icA + 2 <= 15) ? icA + 2 : 15)); \
            int nk_ = (kk_ + 1) % 5;                                          \
            int st_ = (nk_ * 64 + nic_ * 4) * 4096;                           \
            _Pragma("unroll")                                                 \
            for (int nf = 0; nf < 4; ++nf) {                                  \
                BHN[nf] = *(const half8*)(whiL + st_ + nf * 128);             \
                BLN[nf] = *(const half8*)(wloL + st_ + nf * 128);             \
            }                                                                 \
        }                                                                     \
        {                                                                     \
            const f16* Ab_ = &sm[bufc_][0];                                   \
            int m7_ = (l15 + kcur_) & 7;                                      \
            int sh_ = (l4 ^ m7_) * 8;                                         \
            int sl_ = ((l4 + 4) ^ m7_) * 8;                                   \
            __builtin_amdgcn_s_setprio(1);                                    \
            _Pragma("unroll")                                                 \
            for (int mf = 0; mf < 4; ++mf) {                                  \
                int r_ = wm * 64 + mf * 16 + l15 + kcur_;                     \
                half8 ah = *(const half8*)(Ab_ + r_ * 64 + sh_);              \
                half8 al = *(const half8*)(Ab_ + r_ * 64 + sl_);              \
                half8 ahd = ah * inv64;                                       \
                half8 ald = al * inv64;                                       \
                _Pragma("unroll")                                             \
                for (int nf = 0; nf < 4; ++nf) {                              \
                    acc[mf][nf] = __builtin_amdgcn_mfma_f32_16x16x32_f16(     \
                        ah, BHC[nf], acc[mf][nf], 0, 0, 0);                   \
                    acc[mf][nf] = __builtin_amdgcn_mfma_f32_16x16x32_f16(     \
                        ald, BHC[nf], acc[mf][nf], 0, 0, 0);                  \
                    acc[mf][nf] = __builtin_amdgcn_mfma_f32_16x16x32_f16(     \
                        ahd, BLC[nf], acc[mf][nf], 0, 0, 0);                  \
                }                                                             \
            }                                                                 \
            __builtin_amdgcn_s_setprio(0);                                    \
        }                                                                     \
        if (kk_ == 4 || kk_ == 9) __syncthreads();                            \
    } while (0)

    for (int ic2 = 0; ic2 < 8; ++ic2) {
        int icA = ic2 * 2;
        int icB = icA + 1;
        CONV_STEP(0, bhA, blA, bhB, blB);
        CONV_STEP(1, bhB, blB, bhA, blA);
        CONV_STEP(2, bhA, blA, bhB, blB);
        CONV_STEP(3, bhB, blB, bhA, blA);
        CONV_STEP(4, bhA, blA, bhB, blB);
        CONV_STEP(5, bhB, blB, bhA, blA);
        CONV_STEP(6, bhA, blA, bhB, blB);
        CONV_STEP(7, bhB, blB, bhA, blA);
        CONV_STEP(8, bhA, blA, bhB, blB);
        CONV_STEP(9, bhB, blB, bhA, blA);
    }
#undef CONV_STEP

    // epilogue: relu(c+cb)*lw, reduce over o (16 lanes), scatter rows
    float cb[4], lw[4];
#pragma unroll
    for (int nf = 0; nf < 4; ++nf) {
        int o = o0 + wn * 64 + nf * 16 + l15;
        cb[nf] = conv_b[o];
        lw[nf] = lin_w[o];
    }
    float* plb = pl + (size_t)(nb * 2 + wn) * (B_ * T_) + b * T_;
#pragma unroll
    for (int mf = 0; mf < 4; ++mf) {
#pragma unroll
        for (int reg = 0; reg < 4; ++reg) {
            float v = 0.f;
#pragma unroll
            for (int nf = 0; nf < 4; ++nf) {
                float c = acc[mf][nf][reg];
                v += fmaxf(c + cb[nf], 0.f) * lw[nf];
            }
            v += __shfl_xor(v, 1);
            v += __shfl_xor(v, 2);
            v += __shfl_xor(v, 4);
            v += __shfl_xor(v, 8);
            int trow = t0 + wm * 64 + mf * 16 + l4 * 4 + reg;
            if (l15 == reg && trow < T_) plb[trow] = v;
        }
    }
}

// ---------------- PATH B conv (fallback, in-kernel conversion) -------------
#define A_ROWS 132
#define ALO_OFF_E  8448
#define WB_OFF_E   16896
#define WB_ARR_E   4096

__global__ __launch_bounds__(256, 2) void conv_alpha_mfma_b(
    const float* __restrict__ hs, const f16* __restrict__ whi_g,
    const f16* __restrict__ wlo_g, const float* __restrict__ conv_b,
    const float* __restrict__ lin_w, float* __restrict__ pl)
{
    __shared__ f16 sm[33280];
    f16* Ahi = sm;
    f16* Alo = sm + ALO_OFF_E;
    f16* Wb  = sm + WB_OFF_E;

    int tid = threadIdx.x;
    int bid = blockIdx.x;
    int nb  = bid & 3;
    int mtg = bid >> 2;
    int b   = mtg / 24;
    int mt  = mtg - b * 24;
    int t0  = mt * 128;

    int wid = tid >> 6, l = tid & 63;
    int wm = wid >> 1, wn = wid & 1;
    int l15 = l & 15, l4 = l >> 4;

    const float* hb = hs + (size_t)b * T_ * C_;
    int o0 = nb * 128;

    floatx4 acc1[4][4], acc2[4][4];
#pragma unroll
    for (int mf = 0; mf < 4; ++mf)
#pragma unroll
        for (int nf = 0; nf < 4; ++nf) {
            acc1[mf][nf] = (floatx4)0.f;
            acc2[mf][nf] = (floatx4)0.f;
        }

    auto issue_w = [&](int s2) {
        int buf = s2 & 1;
        int ic2 = s2 / 10, kk2 = s2 % 10;
        int k2 = kk2 >> 1, sub2 = kk2 & 1;
        int i8b = ic2 * 8 + sub2 * 4;
#pragma unroll
        for (int rr = 0; rr < 4; ++rr) {
            int r = wid * 4 + rr;
            int arr = r >> 3, kc = (r >> 1) & 3, oh = r & 1;
            const f16* gsrc = (arr ? wlo_g : whi_g) +
                ((size_t)((k2 * 64 + i8b + kc) * 512 + o0 + oh * 64 + l)) * 8;
            f16* ldst = Wb + (buf * 2 + arr) * WB_ARR_E + (kc * 128 + oh * 64) * 8;
            __builtin_amdgcn_global_load_lds((const GLOBAL_AS void*)gsrc,
                                             (LDS_AS void*)ldst, 16, 0, 0);
        }
    };

    issue_w(0);

    for (int s = 0; s < 80; ++s) {
        int ic = s / 10, kk = s % 10;
        int k = kk >> 1, sub = kk & 1;
        int buf = s & 1;

        if (kk == 0) {
            int i0 = ic * 64;
            for (int j = tid; j < A_ROWS * 8; j += 256) {
                int r = j >> 3, c = j & 7;
                int t = t0 - 2 + r;
                float4 v0 = make_float4(0.f, 0.f, 0.f, 0.f);
                float4 v1 = v0;
                if ((unsigned)t < (unsigned)T_) {
                    const float4* p = (const float4*)(hb + (size_t)t * C_ + i0 + c * 8);
                    v0 = p[0]; v1 = p[1];
                }
                float vv[8] = {v0.x, v0.y, v0.z, v0.w, v1.x, v1.y, v1.z, v1.w};
                half8 hh, ll;
#pragma unroll
                for (int q = 0; q < 8; ++q) {
                    f16 x = (f16)vv[q];
                    hh[q] = x;
                    ll[q] = (f16)((vv[q] - (float)x) * LOSC);
                }
                int off = r * 64 + (c ^ (r & 7)) * 8;
                *(half8*)(Ahi + off) = hh;
                *(half8*)(Alo + off) = ll;
            }
            __syncthreads();
        }

        if (s + 1 < 80) issue_w(s + 1);

        half8 ah[4], al[4], bh[4], bl[4];
#pragma unroll
        for (int f = 0; f < 4; ++f) {
            int ar = wm * 64 + f * 16 + l15 + k;
            int aoff = ar * 64 + ((((sub << 2) | l4) ^ (ar & 7)) << 3);
            ah[f] = *(const half8*)(Ahi + aoff);
            al[f] = *(const half8*)(Alo + aoff);
            int wrow = l4 * 128 + wn * 64 + f * 16 + l15;
            bh[f] = *(const half8*)(Wb + (buf * 2 + 0) * WB_ARR_E + wrow * 8);
            bl[f] = *(const half8*)(Wb + (buf * 2 + 1) * WB_ARR_E + wrow * 8);
        }
        __builtin_amdgcn_s_setprio(1);
#pragma unroll
        for (int mf = 0; mf < 4; ++mf)
#pragma unroll
            for (int nf = 0; nf < 4; ++nf) {
                acc1[mf][nf] = __builtin_amdgcn_mfma_f32_16x16x32_f16(
                    ah[mf], bh[nf], acc1[mf][nf], 0, 0, 0);
                acc2[mf][nf] = __builtin_amdgcn_mfma_f32_16x16x32_f16(
                    al[mf], bh[nf], acc2[mf][nf], 0, 0, 0);
                acc2[mf][nf] = __builtin_amdgcn_mfma_f32_16x16x32_f16(
                    ah[mf], bl[nf], acc2[mf][nf], 0, 0, 0);
            }
        __builtin_amdgcn_s_setprio(0);
        __syncthreads();
    }

    float cb[4], lw[4];
#pragma unroll
    for (int nf = 0; nf < 4; ++nf) {
        int o = o0 + wn * 64 + nf * 16 + l15;
        cb[nf] = conv_b[o];
        lw[nf] = lin_w[o];
    }
    float* plb = pl + (size_t)(nb * 2 + wn) * (B_ * T_) + b * T_;
#pragma unroll
    for (int mf = 0; mf < 4; ++mf) {
#pragma unroll
        for (int reg = 0; reg < 4; ++reg) {
            float v = 0.f;
#pragma unroll
            for (int nf = 0; nf < 4; ++nf) {
                float c = acc1[mf][nf][reg] + acc2[mf][nf][reg] * (1.0f / LOSC);
                v += fmaxf(c + cb[nf], 0.f) * lw[nf];
            }
            v += __shfl_xor(v, 1);
            v += __shfl_xor(v, 2);
            v += __shfl_xor(v, 4);
            v += __shfl_xor(v, 8);
            int trow = t0 + wm * 64 + mf * 16 + l4 * 4 + reg;
            if (l15 == reg && trow < T_) plb[trow] = v;
        }
    }
}

// ---------------- combine partials + sigmoid -> alpha ----------------------
__global__ __launch_bounds__(256) void alpha_combine_kernel(
    const float* __restrict__ pl, const float* __restrict__ lin_b,
    float* __restrict__ alpha)
{
    int idx = blockIdx.x * 256 + threadIdx.x;
    if (idx >= B_ * T_) return;
    float s = lin_b[0];
#pragma unroll
    for (int p = 0; p < 8; ++p) s += pl[(size_t)p * (B_ * T_) + idx];
    alpha[idx] = 1.f / (1.f + expf(-s));
}

// ---------------- sequential CIF scan (exact fp32 ref semantics) -----------
__global__ __launch_bounds__(64) void scan_kernel(
    float* __restrict__ alpha, const int* __restrict__ mask,
    int2* __restrict__ seg_i, float2* __restrict__ seg_w,
    int* __restrict__ total_rows, float* __restrict__ out_loss)
{
    int lane = threadIdx.x;
    float lsum = 0.f;
    if (lane < B_) {
        const float4* ap = (const float4*)(alpha + lane * T_);
        const int4*   mp = (const int4*)(mask + lane * T_);
        float* astore = alpha + lane * T_;
        int2*   si = seg_i + lane * T_;
        float2* sw = seg_w + lane * T_;

        float acc = 0.f, leftover = 0.f;
        int nf = 0, prev_t = -1;

        float4 c0 = ap[0], c1 = ap[1];
        int4   m0 = mp[0], m1 = mp[1];
        for (int tc = 0; tc < T_ / 8; ++tc) {
            float4 n0, n1; int4 nm0, nm1;
            if (tc + 1 < T_ / 8) {
                n0 = ap[(tc + 1) * 2]; n1 = ap[(tc + 1) * 2 + 1];
                nm0 = mp[(tc + 1) * 2]; nm1 = mp[(tc + 1) * 2 + 1];
            }
            float av[8] = {c0.x, c0.y, c0.z, c0.w, c1.x, c1.y, c1.z, c1.w};
            int   mv[8] = {m0.x, m0.y, m0.z, m0.w, m1.x, m1.y, m1.z, m1.w};
#pragma unroll
            for (int u = 0; u < 8; ++u) {
                int t = tc * 8 + u;
                float araw = av[u];
                lsum += araw;
                float a = (mv[u] != 0) ? araw : 0.f;
                astore[t] = a;
                float acc2 = acc + a;
                float a1 = THf - acc;
                if (acc2 >= THf) {
                    si[nf] = make_int2(prev_t, t);
                    sw[nf] = make_float2(leftover, a1);
                    float rem = a - a1;
                    leftover = rem;
                    acc = rem;
                    prev_t = t;
                    ++nf;
                } else {
                    acc = acc2;
                }
            }
            c0 = n0; c1 = n1; m0 = nm0; m1 = nm1;
        }
        int tot = nf;
        if (acc >= 0.5f * THf) {
            si[nf] = make_int2(prev_t, T_);
            sw[nf] = make_float2(leftover, 0.f);
            ++tot;
        }
        total_rows[lane] = tot;
        lsum = fabsf(lsum);
    }
#pragma unroll
    for (int off = 16; off >= 1; off >>= 1) lsum += __shfl_down(lsum, off);
    if (lane == 0) out_loss[0] = lsum;
}

// ---------------- segmented weighted emission + zero fill ------------------
__global__ __launch_bounds__(128) void emit_kernel(
    const float* __restrict__ hs, const float* __restrict__ alpha,
    const int2* __restrict__ seg_i, const float2* __restrict__ seg_w,
    const int* __restrict__ total_rows, float* __restrict__ out)
{
    int blk = blockIdx.x;
    int b = blk / T_;
    int r = blk % T_;
    int tid = threadIdx.x;

    float4* cs4 = (float4*)(out + ((size_t)b * T_ + r) * C_);
    float* maskp = out + MASK_OFF + (size_t)b * T_ + r;
    int tot = total_rows[b];

    if (r >= tot) {
        float4 z; z.x = 0.f; z.y = 0.f; z.z = 0.f; z.w = 0.f;
        cs4[tid] = z;
        if (tid == 0) *maskp = 0.f;
        return;
    }
    int2   si = seg_i[b * T_ + r];
    float2 sw = seg_w[b * T_ + r];
    const float4* hb = (const float4*)(hs + (size_t)b * T_ * C_);
    const float*  ab = alpha + b * T_;

    float4 acc; acc.x = 0.f; acc.y = 0.f; acc.z = 0.f; acc.w = 0.f;
    int ts = si.x, te = si.y;
    if (ts >= 0) {
        float4 h = hb[(size_t)ts * (C_ / 4) + tid];
        acc.x = sw.x * h.x; acc.y = sw.x * h.y; acc.z = sw.x * h.z; acc.w = sw.x * h.w;
    }
    for (int t = ts + 1; t < te; ++t) {
        float a = ab[t];
        float4 h = hb[(size_t)t * (C_ / 4) + tid];
        acc.x = fmaf(a, h.x, acc.x); acc.y = fmaf(a, h.y, acc.y);
        acc.z = fmaf(a, h.z, acc.z); acc.w = fmaf(a, h.w, acc.w);
    }
    if (te < T_) {
        float4 h = hb[(size_t)te * (C_ / 4) + tid];
        acc.x = fmaf(sw.y, h.x, acc.x); acc.y = fmaf(sw.y, h.y, acc.y);
        acc.z = fmaf(sw.y, h.z, acc.z); acc.w = fmaf(sw.y, h.w, acc.w);
    }
    cs4[tid] = acc;
    if (tid == 0) *maskp = 1.f;
}

// ---------------- launch ---------------------------------------------------
extern "C" void kernel_launch(void* const* d_in, const int* in_sizes, int n_in,
                              void* d_out, int out_size, void* d_ws, size_t ws_size,
                              hipStream_t stream)
{
    const float* hs     = (const float*)d_in[0];
    const int*   hmask  = (const int*)d_in[1];
    const float* conv_w = (const float*)d_in[2];
    const float* conv_b = (const float*)d_in[3];
    const float* lin_w  = (const float*)d_in[4];
    const float* lin_b  = (const float*)d_in[5];
    float* out = (float*)d_out;
    char*  ws  = (char*)d_ws;

    if (ws_size >= (size_t)A_WS_NEED) {
        f16*    hs16  = (f16*)ws;
        f16*    whi   = (f16*)(ws + A_WHI_OFF);
        f16*    wlo   = (f16*)(ws + A_WLO_OFF);
        float*  pl    = (float*)(ws + A_PL_OFF);
        float*  alpha = (float*)(ws + A_ALPHA_OFF);
        int2*   seg_i = (int2*)(ws + A_SEGI_OFF);
        float2* seg_w = (float2*)(ws + A_SEGW_OFF);
        int*    tot   = (int*)(ws + A_TOT_OFF);

        prep_kernel<<<NB_HS + NB_W, 256, 0, stream>>>(hs, hs16, conv_w, whi, wlo);
        conv_alpha_mfma_a<<<B_ * 24 * 4, 256, 0, stream>>>(hs16, whi, wlo, conv_b,
                                                           lin_w, pl);
        alpha_combine_kernel<<<(B_ * T_ + 255) / 256, 256, 0, stream>>>(pl, lin_b, alpha);
        scan_kernel<<<1, 64, 0, stream>>>(alpha, hmask, seg_i, seg_w, tot, out + LOSS_OFF);
        emit_kernel<<<B_ * T_, 128, 0, stream>>>(hs, alpha, seg_i, seg_w, tot, out);
    } else {
        f16*    whi   = (f16*)(ws + B_WHI_OFF);
        f16*    wlo   = (f16*)(ws + B_WLO_OFF);
        float*  pl    = (float*)(ws + B_PL_OFF);
        float*  alpha = (float*)(ws + B_ALPHA_OFF);
        int2*   seg_i = (int2*)(ws + B_SEGI_OFF);
        float2* seg_w = (float2*)(ws + B_SEGW_OFF);
        int*    tot   = (int*)(ws + B_TOT_OFF);

        prep_kernel<<<NB_HS + NB_W, 256, 0, stream>>>(hs, (f16*)ws, conv_w, whi, wlo);
        conv_alpha_mfma_b<<<B_ * 24 * 4, 256, 0, stream>>>(hs, whi, wlo, conv_b,
                                                           lin_w, pl);
        alpha_combine_kernel<<<(B_ * T_ + 255) / 256, 256, 0, stream>>>(pl, lin_b, alpha);
        scan_kernel<<<1, 64, 0, stream>>>(alpha, hmask, seg_i, seg_w, tot, out + LOSS_OFF);
        emit_kernel<<<B_ * T_, 128, 0, stream>>>(hs, alpha, seg_i, seg_w, tot, out);
    }
}

// Round 10
// 943.480 us; speedup vs baseline: 1.2433x; 1.0513x over previous
//
#include <hip/hip_runtime.h>
#include <math.h>

#define B_ 32
#define T_ 3000
#define C_ 512
#define THf 1.0f
#define KW 2560   // 5*512 flattened conv K

typedef _Float16 f16;
typedef _Float16 half8 __attribute__((ext_vector_type(8)));
typedef float floatx4 __attribute__((ext_vector_type(4)));

#define GLOBAL_AS __attribute__((address_space(1)))
#define LDS_AS __attribute__((address_space(3)))

#define CS_SIZE  ((size_t)B_ * T_ * C_)
#define MASK_OFF CS_SIZE
#define LOSS_OFF (CS_SIZE + (size_t)B_ * T_)

#define LOSC 64.0f   // lo-part scale 2^6 (f16-normal; /64 exact)

// ---- ws layout (~10.3 MB) ----
#define WHI_OFF   0
#define WLO_OFF   2621440
#define PL_OFF    5242880
#define ALPHA_OFF 8314880
#define SEGI_OFF  8698880
#define SEGW_OFF  9466880
#define TOT_OFF   10234880

// ---------------- W prep: [o][i][k] fp32 -> [k][i8][o][ie] f16 hi/lo64 -----
__global__ __launch_bounds__(256) void w_prep_kernel(
    const float* __restrict__ W, f16* __restrict__ whi, f16* __restrict__ wlo)
{
    int idx = blockIdx.x * 256 + threadIdx.x;
    if (idx >= 512 * KW) return;
    int ie = idx & 7;
    int o  = (idx >> 3) & 511;
    int i8 = (idx >> 12) & 63;
    int k  = idx >> 18;
    int i  = i8 * 8 + ie;
    float w = W[o * KW + i * 5 + k];
    f16 h = (f16)w;
    whi[idx] = h;
    wlo[idx] = (f16)((w - (float)h) * LOSC);
}

// ---------------- conv: fp32-A reg-stage + in-kernel split, W-in-regs ------
// block 128t x 128o, 4 waves (2m x 2n) of 64x64; K=32/step, 80 steps.
// LDS: A dbuf 2 x 8704 f16 = 34,816 B (136 rows x 64, XOR-swizzled chunks).
__global__ __launch_bounds__(256, 2) void conv_alpha_mfma_a(
    const float* __restrict__ hs, const f16* __restrict__ whi_g,
    const f16* __restrict__ wlo_g, const float* __restrict__ conv_b,
    const float* __restrict__ lin_w, float* __restrict__ pl)
{
    __shared__ f16 sm[2][8704];

    int tid  = threadIdx.x;
    int orig = blockIdx.x;
    int bid  = (orig & 7) * 384 + (orig >> 3);   // XCD-chunk swizzle (3072%8==0)
    int nb  = bid & 3;
    int mtg = bid >> 2;
    int b   = mtg / 24;
    int mt  = mtg - b * 24;
    int t0  = mt * 128;

    int wid = tid >> 6, l = tid & 63;
    int wm = wid >> 1, wn = wid & 1;
    int l15 = l & 15, l4 = l >> 4;
    int o0 = nb * 128;

    const float* hb = hs + (size_t)b * T_ * C_;

    floatx4 acc[4][4];
#pragma unroll
    for (int mf = 0; mf < 4; ++mf)
#pragma unroll
        for (int nf = 0; nf < 4; ++nf) acc[mf][nf] = (floatx4)0.f;

    // ---- T14 async A staging: load fp32 -> regs (early), convert+write (late)
    // 136 rows x 4 units of 8 floats = 544 units; thread j covers <=3 units.
    float4 sA[3][2];
    auto stage_load = [&](int icn) {
#pragma unroll
        for (int u = 0; u < 3; ++u) {
            int j = tid + u * 256;
            float4 z = make_float4(0.f, 0.f, 0.f, 0.f);
            sA[u][0] = z; sA[u][1] = z;
            if (j < 544) {
                int r = j >> 2, c = j & 3;
                int t = t0 - 2 + r;
                if ((unsigned)t < 3000u) {
                    const float4* p =
                        (const float4*)(hb + (size_t)t * C_ + icn * 32 + c * 8);
                    sA[u][0] = p[0];
                    sA[u][1] = p[1];
                }
            }
        }
    };
    auto stage_write = [&](int abuf) {
#pragma unroll
        for (int u = 0; u < 3; ++u) {
            int j = tid + u * 256;
            if (j < 544) {
                int r = j >> 2, c = j & 3;
                float vv[8] = {sA[u][0].x, sA[u][0].y, sA[u][0].z, sA[u][0].w,
                               sA[u][1].x, sA[u][1].y, sA[u][1].z, sA[u][1].w};
                half8 hh, ll;
#pragma unroll
                for (int q = 0; q < 8; ++q) {
                    f16 x = (f16)vv[q];
                    hh[q] = x;
                    ll[q] = (f16)((vv[q] - (float)x) * LOSC);
                }
                f16* base = &sm[abuf][0] + r * 64;
                int swz = r & 7;   // == (t+2)&7 since t0 % 8 == 0
                *(half8*)(base + (((c)     ^ swz) << 3)) = hh;
                *(half8*)(base + (((c + 4) ^ swz) << 3)) = ll;
            }
        }
    };

    // per-lane W base (elements): covers (l4 -> i8 sub, o-lane)
    const f16* whiL = whi_g + ((l4 * 512) + o0 + wn * 64 + l15) * 8;
    const f16* wloL = wlo_g + ((l4 * 512) + o0 + wn * 64 + l15) * 8;

    const f16 inv64 = (f16)0.015625f;

    half8 bhA[4], blA[4], bhB[4], blB[4];

    // prologue: stage A(0) into buf0; load W(step 0) into set A
    stage_load(0);
#pragma unroll
    for (int nf = 0; nf < 4; ++nf) {
        bhA[nf] = *(const half8*)(whiL + nf * 128);
        blA[nf] = *(const half8*)(wloL + nf * 128);
    }
    stage_write(0);
    __syncthreads();

#define CONV_STEP(KK, BHC, BLC, BHN, BLN)                                     \
    do {                                                                      \
        const int kk_ = (KK);                                                 \
        const int kcur_ = kk_ % 5;                                            \
        const int bufc_ = (kk_ < 5) ? 0 : 1;                                  \
        if (kk_ == 0) stage_load(icB);                                        \
        if (kk_ == 3) stage_write(1);                                         \
        if (kk_ == 5) stage_load((icA + 2 <= 15) ? icA + 2 : 15);             \
        if (kk_ == 8) stage_write(0);                                         \
        {                                                                     \
            int nic_ = (kk_ + 1 < 5) ? icA                                    \
                       : ((kk_ + 1 < 10) ? icB                                \
                                         : ((icA + 2 <= 15) ? icA + 2 : 15)); \
            int nk_ = (kk_ + 1) % 5;                                          \
            int st_ = (nk_ * 64 + nic_ * 4) * 4096;                           \
            _Pragma("unroll")                                                 \
            for (int nf = 0; nf < 4; ++nf) {                                  \
                BHN[nf] = *(const half8*)(whiL + st_ + nf * 128);             \
                BLN[nf] = *(const half8*)(wloL + st_ + nf * 128);             \
            }                                                                 \
        }                                                                     \
        {                                                                     \
            const f16* Ab_ = &sm[bufc_][0];                                   \
            int m7_ = (l15 + kcur_) & 7;                                      \
            int sh_ = (l4 ^ m7_) * 8;                                         \
            int sl_ = ((l4 + 4) ^ m7_) * 8;                                   \
            __builtin_amdgcn_s_setprio(1);                                    \
            _Pragma("unroll")                                                 \
            for (int mf = 0; mf < 4; ++mf) {                                  \
                int r_ = wm * 64 + mf * 16 + l15 + kcur_;                     \
                half8 ah = *(const half8*)(Ab_ + r_ * 64 + sh_);              \
                half8 al = *(const half8*)(Ab_ + r_ * 64 + sl_);              \
                half8 ahd = ah * inv64;                                       \
                half8 ald = al * inv64;                                       \
                _Pragma("unroll")                                             \
                for (int nf = 0; nf < 4; ++nf) {                              \
                    acc[mf][nf] = __builtin_amdgcn_mfma_f32_16x16x32_f16(     \
                        ah, BHC[nf], acc[mf][nf], 0, 0, 0);                   \
                    acc[mf][nf] = __builtin_amdgcn_mfma_f32_16x16x32_f16(     \
                        ald, BHC[nf], acc[mf][nf], 0, 0, 0);                  \
                    acc[mf][nf] = __builtin_amdgcn_mfma_f32_16x16x32_f16(     \
                        ahd, BLC[nf], acc[mf][nf], 0, 0, 0);                  \
                }                                                             \
            }                                                                 \
            __builtin_amdgcn_s_setprio(0);                                    \
        }                                                                     \
        if (kk_ == 4 || kk_ == 9) __syncthreads();                            \
    } while (0)

    for (int ic2 = 0; ic2 < 8; ++ic2) {
        int icA = ic2 * 2;
        int icB = icA + 1;
        CONV_STEP(0, bhA, blA, bhB, blB);
        CONV_STEP(1, bhB, blB, bhA, blA);
        CONV_STEP(2, bhA, blA, bhB, blB);
        CONV_STEP(3, bhB, blB, bhA, blA);
        CONV_STEP(4, bhA, blA, bhB, blB);
        CONV_STEP(5, bhB, blB, bhA, blA);
        CONV_STEP(6, bhA, blA, bhB, blB);
        CONV_STEP(7, bhB, blB, bhA, blA);
        CONV_STEP(8, bhA, blA, bhB, blB);
        CONV_STEP(9, bhB, blB, bhA, blA);
    }
#undef CONV_STEP

    // epilogue: relu(c+cb)*lw, reduce over o (16 lanes), scatter rows
    float cb[4], lw[4];
#pragma unroll
    for (int nf = 0; nf < 4; ++nf) {
        int o = o0 + wn * 64 + nf * 16 + l15;
        cb[nf] = conv_b[o];
        lw[nf] = lin_w[o];
    }
    float* plb = pl + (size_t)(nb * 2 + wn) * (B_ * T_) + b * T_;
#pragma unroll
    for (int mf = 0; mf < 4; ++mf) {
#pragma unroll
        for (int reg = 0; reg < 4; ++reg) {
            float v = 0.f;
#pragma unroll
            for (int nf = 0; nf < 4; ++nf) {
                float c = acc[mf][nf][reg];
                v += fmaxf(c + cb[nf], 0.f) * lw[nf];
            }
            v += __shfl_xor(v, 1);
            v += __shfl_xor(v, 2);
            v += __shfl_xor(v, 4);
            v += __shfl_xor(v, 8);
            int trow = t0 + wm * 64 + mf * 16 + l4 * 4 + reg;
            if (l15 == reg && trow < T_) plb[trow] = v;
        }
    }
}

// ---------------- combine partials + sigmoid -> alpha ----------------------
__global__ __launch_bounds__(256) void alpha_combine_kernel(
    const float* __restrict__ pl, const float* __restrict__ lin_b,
    float* __restrict__ alpha)
{
    int idx = blockIdx.x * 256 + threadIdx.x;
    if (idx >= B_ * T_) return;
    float s = lin_b[0];
#pragma unroll
    for (int p = 0; p < 8; ++p) s += pl[(size_t)p * (B_ * T_) + idx];
    alpha[idx] = 1.f / (1.f + expf(-s));
}

// ---------------- sequential CIF scan (exact fp32 ref semantics) -----------
__global__ __launch_bounds__(64) void scan_kernel(
    float* __restrict__ alpha, const int* __restrict__ mask,
    int2* __restrict__ seg_i, float2* __restrict__ seg_w,
    int* __restrict__ total_rows, float* __restrict__ out_loss)
{
    int lane = threadIdx.x;
    float lsum = 0.f;
    if (lane < B_) {
        const float4* ap = (const float4*)(alpha + lane * T_);
        const int4*   mp = (const int4*)(mask + lane * T_);
        float* astore = alpha + lane * T_;
        int2*   si = seg_i + lane * T_;
        float2* sw = seg_w + lane * T_;

        float acc = 0.f, leftover = 0.f;
        int nf = 0, prev_t = -1;

        float4 c0 = ap[0], c1 = ap[1];
        int4   m0 = mp[0], m1 = mp[1];
        for (int tc = 0; tc < T_ / 8; ++tc) {
            float4 n0, n1; int4 nm0, nm1;
            if (tc + 1 < T_ / 8) {
                n0 = ap[(tc + 1) * 2]; n1 = ap[(tc + 1) * 2 + 1];
                nm0 = mp[(tc + 1) * 2]; nm1 = mp[(tc + 1) * 2 + 1];
            }
            float av[8] = {c0.x, c0.y, c0.z, c0.w, c1.x, c1.y, c1.z, c1.w};
            int   mv[8] = {m0.x, m0.y, m0.z, m0.w, m1.x, m1.y, m1.z, m1.w};
#pragma unroll
            for (int u = 0; u < 8; ++u) {
                int t = tc * 8 + u;
                float araw = av[u];
                lsum += araw;
                float a = (mv[u] != 0) ? araw : 0.f;
                astore[t] = a;
                float acc2 = acc + a;
                float a1 = THf - acc;
                if (acc2 >= THf) {
                    si[nf] = make_int2(prev_t, t);
                    sw[nf] = make_float2(leftover, a1);
                    float rem = a - a1;
                    leftover = rem;
                    acc = rem;
                    prev_t = t;
                    ++nf;
                } else {
                    acc = acc2;
                }
            }
            c0 = n0; c1 = n1; m0 = nm0; m1 = nm1;
        }
        int tot = nf;
        if (acc >= 0.5f * THf) {
            si[nf] = make_int2(prev_t, T_);
            sw[nf] = make_float2(leftover, 0.f);
            ++tot;
        }
        total_rows[lane] = tot;
        lsum = fabsf(lsum);
    }
#pragma unroll
    for (int off = 16; off >= 1; off >>= 1) lsum += __shfl_down(lsum, off);
    if (lane == 0) out_loss[0] = lsum;
}

// ---------------- segmented weighted emission + zero fill ------------------
__global__ __launch_bounds__(128) void emit_kernel(
    const float* __restrict__ hs, const float* __restrict__ alpha,
    const int2* __restrict__ seg_i, const float2* __restrict__ seg_w,
    const int* __restrict__ total_rows, float* __restrict__ out)
{
    int blk = blockIdx.x;
    int b = blk / T_;
    int r = blk % T_;
    int tid = threadIdx.x;

    float4* cs4 = (float4*)(out + ((size_t)b * T_ + r) * C_);
    float* maskp = out + MASK_OFF + (size_t)b * T_ + r;
    int tot = total_rows[b];

    if (r >= tot) {
        float4 z; z.x = 0.f; z.y = 0.f; z.z = 0.f; z.w = 0.f;
        cs4[tid] = z;
        if (tid == 0) *maskp = 0.f;
        return;
    }
    int2   si = seg_i[b * T_ + r];
    float2 sw = seg_w[b * T_ + r];
    const float4* hb = (const float4*)(hs + (size_t)b * T_ * C_);
    const float*  ab = alpha + b * T_;

    float4 acc; acc.x = 0.f; acc.y = 0.f; acc.z = 0.f; acc.w = 0.f;
    int ts = si.x, te = si.y;
    if (ts >= 0) {
        float4 h = hb[(size_t)ts * (C_ / 4) + tid];
        acc.x = sw.x * h.x; acc.y = sw.x * h.y; acc.z = sw.x * h.z; acc.w = sw.x * h.w;
    }
    for (int t = ts + 1; t < te; ++t) {
        float a = ab[t];
        float4 h = hb[(size_t)t * (C_ / 4) + tid];
        acc.x = fmaf(a, h.x, acc.x); acc.y = fmaf(a, h.y, acc.y);
        acc.z = fmaf(a, h.z, acc.z); acc.w = fmaf(a, h.w, acc.w);
    }
    if (te < T_) {
        float4 h = hb[(size_t)te * (C_ / 4) + tid];
        acc.x = fmaf(sw.y, h.x, acc.x); acc.y = fmaf(sw.y, h.y, acc.y);
        acc.z = fmaf(sw.y, h.z, acc.z); acc.w = fmaf(sw.y, h.w, acc.w);
    }
    cs4[tid] = acc;
    if (tid == 0) *maskp = 1.f;
}

// ---------------- launch ---------------------------------------------------
extern "C" void kernel_launch(void* const* d_in, const int* in_sizes, int n_in,
                              void* d_out, int out_size, void* d_ws, size_t ws_size,
                              hipStream_t stream)
{
    const float* hs     = (const float*)d_in[0];
    const int*   hmask  = (const int*)d_in[1];
    const float* conv_w = (const float*)d_in[2];
    const float* conv_b = (const float*)d_in[3];
    const float* lin_w  = (const float*)d_in[4];
    const float* lin_b  = (const float*)d_in[5];
    float* out = (float*)d_out;
    char*  ws  = (char*)d_ws;

    f16*    whi   = (f16*)(ws + WHI_OFF);
    f16*    wlo   = (f16*)(ws + WLO_OFF);
    float*  pl    = (float*)(ws + PL_OFF);
    float*  alpha = (float*)(ws + ALPHA_OFF);
    int2*   seg_i = (int2*)(ws + SEGI_OFF);
    float2* seg_w = (float2*)(ws + SEGW_OFF);
    int*    tot   = (int*)(ws + TOT_OFF);

    w_prep_kernel<<<(512 * KW + 255) / 256, 256, 0, stream>>>(conv_w, whi, wlo);
    conv_alpha_mfma_a<<<B_ * 24 * 4, 256, 0, stream>>>(hs, whi, wlo, conv_b,
                                                       lin_w, pl);
    alpha_combine_kernel<<<(B_ * T_ + 255) / 256, 256, 0, stream>>>(pl, lin_b, alpha);
    scan_kernel<<<1, 64, 0, stream>>>(alpha, hmask, seg_i, seg_w, tot, out + LOSS_OFF);
    emit_kernel<<<B_ * T_, 128, 0, stream>>>(hs, alpha, seg_i, seg_w, tot, out);
}